// Round 2
// baseline (1727.439 us; speedup 1.0000x reference)
//
#include <hip/hip_runtime.h>
#include <math.h>

#define NB 16
#define L 256
#define H 128
#define HID 128
#define LAMF 20.0f
#define EPSF 1e-8f
#define NITER 20

// async global->LDS, 16B per lane
#define GLL16(gp, lp) __builtin_amdgcn_global_load_lds( \
    (const __attribute__((address_space(1))) unsigned int*)(gp), \
    (__attribute__((address_space(3))) unsigned int*)(lp), 16, 0, 0)
// s_waitcnt encodings (gfx9): vmcnt low [3:0], exp [6:4], lgkm [11:8], vmcnt hi [15:14]
#define WAITVM2() __builtin_amdgcn_s_waitcnt(0x0F72)  // vmcnt(2), lgkm/exp nowait
#define WAITVM0() __builtin_amdgcn_s_waitcnt(0x0F70)  // vmcnt(0)
#define WAITLGKM0() __builtin_amdgcn_s_waitcnt(0xC07F) // lgkmcnt(0), vm/exp nowait

// ---------------------------------------------------------------------------
// K1: scores = tanh(f @ W1 + b1) @ W2 + b2   (unchanged)
// ---------------------------------------------------------------------------
__global__ __launch_bounds__(256) void k_scores(
    const float* __restrict__ f, const float* __restrict__ W1,
    const float* __restrict__ b1, const float* __restrict__ W2,
    const float* __restrict__ b2, float* __restrict__ scores)
{
    __shared__ float As[32][68];
    __shared__ float Bs[32][132];
    const int tid = threadIdx.x;
    const int tx = tid & 31;
    const int ty = tid >> 5;
    const long m0 = (long)blockIdx.x * 64;

    float acc[8][4];
#pragma unroll
    for (int i = 0; i < 8; i++)
#pragma unroll
        for (int c = 0; c < 4; c++) acc[i][c] = 0.f;

    for (int kc = 0; kc < H; kc += 32) {
        {
            const int k = tid & 31, mb = tid >> 5;
#pragma unroll
            for (int r = 0; r < 8; r++) {
                int m = mb + r * 8;
                As[k][m] = f[(m0 + m) * H + kc + k];
            }
        }
        {
#pragma unroll
            for (int r = 0; r < 16; r++) {
                int idx = r * 256 + tid;
                int k = idx >> 7, n = idx & 127;
                Bs[k][n] = W1[(kc + k) * HID + n];
            }
        }
        __syncthreads();
#pragma unroll
        for (int k = 0; k < 32; k++) {
            float4 a0 = *(const float4*)&As[k][ty * 8];
            float4 a1 = *(const float4*)&As[k][ty * 8 + 4];
            float4 bv = *(const float4*)&Bs[k][tx * 4];
            float av[8] = {a0.x, a0.y, a0.z, a0.w, a1.x, a1.y, a1.z, a1.w};
            float bb[4] = {bv.x, bv.y, bv.z, bv.w};
#pragma unroll
            for (int i = 0; i < 8; i++)
#pragma unroll
                for (int c = 0; c < 4; c++)
                    acc[i][c] = fmaf(av[i], bb[c], acc[i][c]);
        }
        __syncthreads();
    }
    float part[8];
#pragma unroll
    for (int i = 0; i < 8; i++) part[i] = 0.f;
#pragma unroll
    for (int c = 0; c < 4; c++) {
        int col = tx * 4 + c;
        float b1v = b1[col], w2v = W2[col];
#pragma unroll
        for (int i = 0; i < 8; i++) {
            float hv = tanhf(acc[i][c] + b1v);
            part[i] = fmaf(hv, w2v, part[i]);
        }
    }
#pragma unroll
    for (int off = 16; off >= 1; off >>= 1)
#pragma unroll
        for (int i = 0; i < 8; i++)
            part[i] += __shfl_xor(part[i], off, 64);
    if (tx == 0) {
        float b2v = b2[0];
#pragma unroll
        for (int i = 0; i < 8; i++) {
            int row = ty * 8 + i;
            scores[m0 + row] = part[i] + b2v;
        }
    }
}

// ---------------------------------------------------------------------------
// K2: C[s,i,j] = dot128(f[s,i,j,:], f[s,j,i,:])  (unchanged)
// ---------------------------------------------------------------------------
__global__ __launch_bounds__(256) void k_cost(
    const float* __restrict__ f, float* __restrict__ C)
{
    const int bid = blockIdx.x;
    const int s = bid >> 8, i = bid & 255;
    const int wave = threadIdx.x >> 6, lane = threadIdx.x & 63;
    const long base_i = ((long)(s * L + i)) * L;
    for (int j4 = i; j4 < L; j4 += 4) {
        int j = j4 + wave;
        if (j < L) {
            const float2 x = *(const float2*)&f[(base_i + j) * (long)H + lane * 2];
            const float2 y = *(const float2*)&f[(((long)(s * L + j)) * L + i) * (long)H + lane * 2];
            float d = fmaf(x.x, y.x, x.y * y.y);
#pragma unroll
            for (int off = 32; off >= 1; off >>= 1) d += __shfl_xor(d, off, 64);
            if (lane == 0) {
                C[base_i + j] = d;
                C[((long)(s * L + j)) * L + i] = d;
            }
        }
    }
}

// ---------------------------------------------------------------------------
// K3: per-sample max |C|  (unchanged)
// ---------------------------------------------------------------------------
__global__ __launch_bounds__(256) void k_absmax(
    const float* __restrict__ C, float* __restrict__ maxabs)
{
    __shared__ float red[256];
    const int s = blockIdx.x, tid = threadIdx.x;
    const float* Cp = C + (long)s * L * L;
    float m = 0.f;
    for (int idx = tid; idx < L * L; idx += 256) m = fmaxf(m, fabsf(Cp[idx]));
    red[tid] = m;
    __syncthreads();
    for (int o = 128; o >= 1; o >>= 1) {
        if (tid < o) red[tid] = fmaxf(red[tid], red[tid + o]);
        __syncthreads();
    }
    if (tid == 0) maxabs[s] = red[0];
}

// ---------------------------------------------------------------------------
// K4: Kmat = exp(-LAM*Cn), KM = Kmat*Cn  (unchanged)
// ---------------------------------------------------------------------------
__global__ __launch_bounds__(512) void k_kmat(
    const float* __restrict__ C, const float* __restrict__ maxabs,
    float* __restrict__ Km, float* __restrict__ KMm)
{
    long idx = (long)blockIdx.x * blockDim.x + threadIdx.x;
    const long tot = (long)NB * L * L;
    for (; idx < tot; idx += (long)gridDim.x * blockDim.x) {
        int s = (int)(idx >> 16);
        float cn = C[idx] / (maxabs[s] + EPSF);
        float kv = __expf(-LAMF * cn);
        Km[idx] = kv;
        KMm[idx] = kv * cn;
    }
}

// ---------------------------------------------------------------------------
// K5: r = softmax(scores row), c = (head+EPS)/rowsum  (unchanged)
// ---------------------------------------------------------------------------
__global__ __launch_bounds__(256) void k_rc(
    const float* __restrict__ scores, const float* __restrict__ head,
    float* __restrict__ R, float* __restrict__ Cd)
{
    __shared__ float red[256];
    const long base = (long)blockIdx.x * L;
    const int t = threadIdx.x;
    float sc = scores[base + t];
    red[t] = sc;
    __syncthreads();
    for (int o = 128; o >= 1; o >>= 1) {
        if (t < o) red[t] = fmaxf(red[t], red[t + o]);
        __syncthreads();
    }
    float mx = red[0];
    __syncthreads();
    float e = __expf(sc - mx);
    red[t] = e;
    __syncthreads();
    for (int o = 128; o >= 1; o >>= 1) {
        if (t < o) red[t] += red[t + o];
        __syncthreads();
    }
    float es = red[0];
    __syncthreads();
    R[base + t] = e / es;
    float hv = head[base + t] + EPSF;
    red[t] = hv;
    __syncthreads();
    for (int o = 128; o >= 1; o >>= 1) {
        if (t < o) red[t] += red[t + o];
        __syncthreads();
    }
    float hs = red[0];
    Cd[base + t] = hv / hs;
}

// ---------------------------------------------------------------------------
// K6: Sinkhorn v2 — wave-private async K staging, zero intra-pass barriers.
// Grid 256 = (sample, 16-col chunk), 512 thr (8 waves). Wave w owns K columns
// [32w,32w+32). K staged per 16-row tile into per-wave LDS double buffers via
// global_load_lds; sync via own vmcnt only. U/T in LDS, stride 16, XOR-pair
// swizzle (j ^ (b&14)) -> conflict-free ds_read_b64. 1 barrier per pass.
// Thread tile: 4 a's x 2 j's. LDS = 32K (Kw) + 16K (Uc) + 16K (Tc) = 64KB.
// ---------------------------------------------------------------------------
__global__ __launch_bounds__(512) void k_sink(
    const float* __restrict__ Km, const float* __restrict__ KMm,
    const float* __restrict__ R, const float* __restrict__ Cd,
    float* __restrict__ lossbuf)
{
    __shared__ __align__(128) float Kw[8 * 2 * 512];   // [wave][buf][16 rows x 32 cols]
    __shared__ __align__(128) float Uc[4096];
    __shared__ __align__(128) float Tc[4096];

    const int bid = blockIdx.x;
    const int s = bid >> 4;
    const int j0 = (bid & 15) * 16;
    const float* Kp  = Km  + (long)s * 65536;
    const float* KMp = KMm + (long)s * 65536;
    const float* Rp  = R  + (long)s * 65536 + (long)j0 * L;
    const float* Cp  = Cd + (long)s * 65536 + (long)j0 * L;

    const int tid  = threadIdx.x;
    const int w    = tid >> 6;
    const int lane = tid & 63;
    const int ta   = lane & 7;    // 0..7  -> a quad
    const int jh   = lane >> 3;   // 0..7  -> j pair
    const int ab   = w * 32 + ta * 4;
    const int jb   = jh * 2;

    // staging offsets: wave tile region is 2KB ([16 rows][128B])
    const int o0 = lane * 16;          // chunk 0 byte offset
    const int o1 = (64 + lane) * 16;   // chunk 1
    char* lbase = (char*)&Kw[w * 1024];
    const int gcol = w * 128;          // byte column offset of this wave's slice

    // invariant per-block row vectors (c and r for our 2 columns)
    const float4 cva = *(const float4*)&Cp[jb * L + ab];
    const float4 cvb = *(const float4*)&Cp[(jb + 1) * L + ab];
    const float4 rva = *(const float4*)&Rp[jb * L + ab];
    const float4 rvb = *(const float4*)&Rp[(jb + 1) * L + ab];
    const float ca[4] = {cva.x, cva.y, cva.z, cva.w};
    const float cb[4] = {cvb.x, cvb.y, cvb.z, cvb.w};
    const float ra[4] = {rva.x, rva.y, rva.z, rva.w};
    const float rb[4] = {rvb.x, rvb.y, rvb.z, rvb.w};

    for (int idx = tid; idx < 4096; idx += 512) Uc[idx] = 1.0f / L;
    __syncthreads();

    float acc[4][2];

    auto stage = [&](const float* Mg, int b0, int buf) {
        const char* g = (const char*)Mg + (size_t)b0 * 1024 + gcol;
        char* l = lbase + (buf << 11);
        GLL16(g + ((o0 >> 7) << 10) + (o0 & 127), l + o0);
        GLL16(g + ((o1 >> 7) << 10) + (o1 & 127), l + o1);
    };

    auto run_pass = [&](const float* __restrict__ Mg, const float* __restrict__ S) {
#pragma unroll
        for (int ai = 0; ai < 4; ai++) { acc[ai][0] = 0.f; acc[ai][1] = 0.f; }
        stage(Mg, 0, 0);
        for (int t = 0; t < 16; t++) {
            WAITLGKM0();                 // our prior-tile ds_reads fully drained
            if (t < 15) {
                stage(Mg, (t + 1) * 16, (t + 1) & 1);
                WAITVM2();               // tile t's two loads have landed
            } else {
                WAITVM0();
            }
            const float* Kb = &Kw[w * 1024 + ((t & 1) << 9)] + ta * 4;
            const float* St = S + (t << 8);
#pragma unroll
            for (int bbi = 0; bbi < 16; bbi++) {
                float4 kv = *(const float4*)&Kb[bbi * 32];
                float2 sv = *(const float2*)&St[bbi * 16 + (jb ^ (bbi & 14))];
                acc[0][0] = fmaf(kv.x, sv.x, acc[0][0]); acc[0][1] = fmaf(kv.x, sv.y, acc[0][1]);
                acc[1][0] = fmaf(kv.y, sv.x, acc[1][0]); acc[1][1] = fmaf(kv.y, sv.y, acc[1][1]);
                acc[2][0] = fmaf(kv.z, sv.x, acc[2][0]); acc[2][1] = fmaf(kv.z, sv.y, acc[2][1]);
                acc[3][0] = fmaf(kv.w, sv.x, acc[3][0]); acc[3][1] = fmaf(kv.w, sv.y, acc[3][1]);
            }
        }
    };

    float lp = 0.f;
    for (int it = 0; it < NITER; it++) {
        // pass A: acc = K @ U ; T = c/(acc+eps)
        run_pass(Kp, Uc);
#pragma unroll
        for (int ai = 0; ai < 4; ai++) {
            const int bI = ab + ai;
            float2 o;
            o.x = ca[ai] / (acc[ai][0] + EPSF);
            o.y = cb[ai] / (acc[ai][1] + EPSF);
            *(float2*)&Tc[bI * 16 + (jb ^ (bI & 14))] = o;
        }
        __syncthreads();
        // pass B: acc = K @ T ; U = r/(acc+eps)
        run_pass(Kp, Tc);
#pragma unroll
        for (int ai = 0; ai < 4; ai++) {
            const int bI = ab + ai;
            float2 o;
            o.x = ra[ai] / (acc[ai][0] + EPSF);
            o.y = rb[ai] / (acc[ai][1] + EPSF);
            *(float2*)&Uc[bI * 16 + (jb ^ (bI & 14))] = o;
        }
        __syncthreads();
    }
    // final V pass: V = c/(K@U+eps) -> Tc
    run_pass(Kp, Uc);
#pragma unroll
    for (int ai = 0; ai < 4; ai++) {
        const int bI = ab + ai;
        float2 o;
        o.x = ca[ai] / (acc[ai][0] + EPSF);
        o.y = cb[ai] / (acc[ai][1] + EPSF);
        *(float2*)&Tc[bI * 16 + (jb ^ (bI & 14))] = o;
    }
    __syncthreads();
    // loss pass: acc = KM @ V ; lp += sum U*acc
    run_pass(KMp, Tc);
#pragma unroll
    for (int ai = 0; ai < 4; ai++) {
        const int bI = ab + ai;
#pragma unroll
        for (int cj = 0; cj < 2; cj++)
            lp += Uc[bI * 16 + ((jb + cj) ^ (bI & 14))] * acc[ai][cj];
    }
    __syncthreads();
    // block reduction (reuse Kw as scratch — staging all drained)
    float* red = Kw;
    red[tid] = lp;
    __syncthreads();
    for (int o = 256; o >= 1; o >>= 1) {
        if (tid < o) red[tid] += red[tid + o];
        __syncthreads();
    }
    if (tid == 0) lossbuf[bid] = red[0];
}

// ---------------------------------------------------------------------------
// K7: final sum  (unchanged)
// ---------------------------------------------------------------------------
__global__ __launch_bounds__(256) void k_final(
    const float* __restrict__ lossbuf, float* __restrict__ out)
{
    __shared__ float red[256];
    int t = threadIdx.x;
    red[t] = lossbuf[t];
    __syncthreads();
    for (int o = 128; o >= 1; o >>= 1) {
        if (t < o) red[t] += red[t + o];
        __syncthreads();
    }
    if (t == 0) out[0] = red[0];
}

extern "C" void kernel_launch(void* const* d_in, const int* in_sizes, int n_in,
                              void* d_out, int out_size, void* d_ws, size_t ws_size,
                              hipStream_t stream)
{
    const float* f    = (const float*)d_in[0];
    const float* head = (const float*)d_in[1];
    const float* W1   = (const float*)d_in[2];
    const float* b1   = (const float*)d_in[3];
    const float* W2   = (const float*)d_in[4];
    const float* b2   = (const float*)d_in[5];
    float* scores = (float*)d_out;
    float* wloss  = scores + (long)NB * L * L;

    float* ws      = (float*)d_ws;
    float* C       = ws;
    float* Km      = ws + 1 * 1048576;
    float* KMm     = ws + 2 * 1048576;
    float* R       = ws + 3 * 1048576;
    float* Cd      = ws + 4 * 1048576;
    float* maxabs  = ws + 5 * 1048576;
    float* lossbuf = maxabs + 64;

    k_scores<<<16384, 256, 0, stream>>>(f, W1, b1, W2, b2, scores);
    k_cost  <<<4096,  256, 0, stream>>>(f, C);
    k_absmax<<<NB,    256, 0, stream>>>(C, maxabs);
    k_kmat  <<<2048,  512, 0, stream>>>(C, maxabs, Km, KMm);
    k_rc    <<<NB * L, 256, 0, stream>>>(scores, head, R, Cd);
    k_sink  <<<NB * 16, 512, 0, stream>>>(Km, KMm, R, Cd, lossbuf);
    k_final <<<1, 256, 0, stream>>>(lossbuf, wloss);
}

// Round 3
// 1595.993 us; speedup vs baseline: 1.0824x; 1.0824x over previous
//
#include <hip/hip_runtime.h>
#include <math.h>

#define NB 16
#define L 256
#define H 128
#define HID 128
#define LAMF 20.0f
#define EPSF 1e-8f
#define NITER 20

// async global->LDS, 16B per lane
#define GLL16(gp, lp) __builtin_amdgcn_global_load_lds( \
    (const __attribute__((address_space(1))) unsigned int*)(gp), \
    (__attribute__((address_space(3))) unsigned int*)(lp), 16, 0, 0)
// s_waitcnt encodings (gfx9): vmcnt low [3:0], exp [6:4], lgkm [11:8], vmcnt hi [15:14]
#define WAITVM4() __builtin_amdgcn_s_waitcnt(0x0F74)  // vmcnt(4), lgkm/exp nowait
#define WAITVM0() __builtin_amdgcn_s_waitcnt(0x0F70)  // vmcnt(0)
#define WAITLGKM0() __builtin_amdgcn_s_waitcnt(0xC07F) // lgkmcnt(0), vm/exp nowait

// ---------------------------------------------------------------------------
// K1: scores = tanh(f @ W1 + b1) @ W2 + b2   (unchanged)
// ---------------------------------------------------------------------------
__global__ __launch_bounds__(256) void k_scores(
    const float* __restrict__ f, const float* __restrict__ W1,
    const float* __restrict__ b1, const float* __restrict__ W2,
    const float* __restrict__ b2, float* __restrict__ scores)
{
    __shared__ float As[32][68];
    __shared__ float Bs[32][132];
    const int tid = threadIdx.x;
    const int tx = tid & 31;
    const int ty = tid >> 5;
    const long m0 = (long)blockIdx.x * 64;

    float acc[8][4];
#pragma unroll
    for (int i = 0; i < 8; i++)
#pragma unroll
        for (int c = 0; c < 4; c++) acc[i][c] = 0.f;

    for (int kc = 0; kc < H; kc += 32) {
        {
            const int k = tid & 31, mb = tid >> 5;
#pragma unroll
            for (int r = 0; r < 8; r++) {
                int m = mb + r * 8;
                As[k][m] = f[(m0 + m) * H + kc + k];
            }
        }
        {
#pragma unroll
            for (int r = 0; r < 16; r++) {
                int idx = r * 256 + tid;
                int k = idx >> 7, n = idx & 127;
                Bs[k][n] = W1[(kc + k) * HID + n];
            }
        }
        __syncthreads();
#pragma unroll
        for (int k = 0; k < 32; k++) {
            float4 a0 = *(const float4*)&As[k][ty * 8];
            float4 a1 = *(const float4*)&As[k][ty * 8 + 4];
            float4 bv = *(const float4*)&Bs[k][tx * 4];
            float av[8] = {a0.x, a0.y, a0.z, a0.w, a1.x, a1.y, a1.z, a1.w};
            float bb[4] = {bv.x, bv.y, bv.z, bv.w};
#pragma unroll
            for (int i = 0; i < 8; i++)
#pragma unroll
                for (int c = 0; c < 4; c++)
                    acc[i][c] = fmaf(av[i], bb[c], acc[i][c]);
        }
        __syncthreads();
    }
    float part[8];
#pragma unroll
    for (int i = 0; i < 8; i++) part[i] = 0.f;
#pragma unroll
    for (int c = 0; c < 4; c++) {
        int col = tx * 4 + c;
        float b1v = b1[col], w2v = W2[col];
#pragma unroll
        for (int i = 0; i < 8; i++) {
            float hv = tanhf(acc[i][c] + b1v);
            part[i] = fmaf(hv, w2v, part[i]);
        }
    }
#pragma unroll
    for (int off = 16; off >= 1; off >>= 1)
#pragma unroll
        for (int i = 0; i < 8; i++)
            part[i] += __shfl_xor(part[i], off, 64);
    if (tx == 0) {
        float b2v = b2[0];
#pragma unroll
        for (int i = 0; i < 8; i++) {
            int row = ty * 8 + i;
            scores[m0 + row] = part[i] + b2v;
        }
    }
}

// ---------------------------------------------------------------------------
// K2: C[s,i,j] = dot128(f[s,i,j,:], f[s,j,i,:])  (unchanged)
// ---------------------------------------------------------------------------
__global__ __launch_bounds__(256) void k_cost(
    const float* __restrict__ f, float* __restrict__ C)
{
    const int bid = blockIdx.x;
    const int s = bid >> 8, i = bid & 255;
    const int wave = threadIdx.x >> 6, lane = threadIdx.x & 63;
    const long base_i = ((long)(s * L + i)) * L;
    for (int j4 = i; j4 < L; j4 += 4) {
        int j = j4 + wave;
        if (j < L) {
            const float2 x = *(const float2*)&f[(base_i + j) * (long)H + lane * 2];
            const float2 y = *(const float2*)&f[(((long)(s * L + j)) * L + i) * (long)H + lane * 2];
            float d = fmaf(x.x, y.x, x.y * y.y);
#pragma unroll
            for (int off = 32; off >= 1; off >>= 1) d += __shfl_xor(d, off, 64);
            if (lane == 0) {
                C[base_i + j] = d;
                C[((long)(s * L + j)) * L + i] = d;
            }
        }
    }
}

// ---------------------------------------------------------------------------
// K3: per-sample max |C|  (unchanged)
// ---------------------------------------------------------------------------
__global__ __launch_bounds__(256) void k_absmax(
    const float* __restrict__ C, float* __restrict__ maxabs)
{
    __shared__ float red[256];
    const int s = blockIdx.x, tid = threadIdx.x;
    const float* Cp = C + (long)s * L * L;
    float m = 0.f;
    for (int idx = tid; idx < L * L; idx += 256) m = fmaxf(m, fabsf(Cp[idx]));
    red[tid] = m;
    __syncthreads();
    for (int o = 128; o >= 1; o >>= 1) {
        if (tid < o) red[tid] = fmaxf(red[tid], red[tid + o]);
        __syncthreads();
    }
    if (tid == 0) maxabs[s] = red[0];
}

// ---------------------------------------------------------------------------
// K4: Kmat = exp(-LAM*Cn), KM = Kmat*Cn  (unchanged)
// ---------------------------------------------------------------------------
__global__ __launch_bounds__(512) void k_kmat(
    const float* __restrict__ C, const float* __restrict__ maxabs,
    float* __restrict__ Km, float* __restrict__ KMm)
{
    long idx = (long)blockIdx.x * blockDim.x + threadIdx.x;
    const long tot = (long)NB * L * L;
    for (; idx < tot; idx += (long)gridDim.x * blockDim.x) {
        int s = (int)(idx >> 16);
        float cn = C[idx] / (maxabs[s] + EPSF);
        float kv = __expf(-LAMF * cn);
        Km[idx] = kv;
        KMm[idx] = kv * cn;
    }
}

// ---------------------------------------------------------------------------
// K5: r = softmax(scores row), c = (head+EPS)/rowsum  (unchanged)
// ---------------------------------------------------------------------------
__global__ __launch_bounds__(256) void k_rc(
    const float* __restrict__ scores, const float* __restrict__ head,
    float* __restrict__ R, float* __restrict__ Cd)
{
    __shared__ float red[256];
    const long base = (long)blockIdx.x * L;
    const int t = threadIdx.x;
    float sc = scores[base + t];
    red[t] = sc;
    __syncthreads();
    for (int o = 128; o >= 1; o >>= 1) {
        if (t < o) red[t] = fmaxf(red[t], red[t + o]);
        __syncthreads();
    }
    float mx = red[0];
    __syncthreads();
    float e = __expf(sc - mx);
    red[t] = e;
    __syncthreads();
    for (int o = 128; o >= 1; o >>= 1) {
        if (t < o) red[t] += red[t + o];
        __syncthreads();
    }
    float es = red[0];
    __syncthreads();
    R[base + t] = e / es;
    float hv = head[base + t] + EPSF;
    red[t] = hv;
    __syncthreads();
    for (int o = 128; o >= 1; o >>= 1) {
        if (t < o) red[t] += red[t + o];
        __syncthreads();
    }
    float hs = red[0];
    Cd[base + t] = hv / hs;
}

// ---------------------------------------------------------------------------
// K6: Sinkhorn v3 — 4a x 4j thread tile (16 FMA per 2 ds_read_b128), b-dim
// split across wave halves (waves 0-3: b in [0,128), waves 4-7: [128,256)),
// per-pass cross-half reduction via LDS scratch. Halves LDS-instr and
// addr-VALU per FLOP vs v2. S vectors stride-20 rows (aligned float4 reads,
// conflict-free; 8-way only on 4 update writes/pass). K staged per 16-row
// tile into per-wave LDS double buffers via global_load_lds (4 loads/tile,
// vmcnt(4)). LDS = 64K (Kw) + 20K (Uc) + 20K (Tc) + 20K (Sc) = 124KB.
// ---------------------------------------------------------------------------
__global__ __launch_bounds__(512) void k_sink(
    const float* __restrict__ Km, const float* __restrict__ KMm,
    const float* __restrict__ R, const float* __restrict__ Cd,
    float* __restrict__ lossbuf)
{
    __shared__ __align__(128) float Kw[16384];  // [wave][buf][16 rows x 64 cols]
    __shared__ __align__(128) float Uc[5120];   // [256 b][20] (16 j + pad)
    __shared__ __align__(128) float Tc[5120];
    __shared__ __align__(128) float Sc[5120];   // reduction scratch

    const int bid = blockIdx.x;
    const int s = bid >> 4;
    const int j0 = (bid & 15) * 16;
    const char* Kpb  = (const char*)(Km  + (long)s * 65536);
    const char* KMpb = (const char*)(KMm + (long)s * 65536);
    const float* Rp  = R  + (long)s * 65536 + (long)j0 * L;
    const float* Cp  = Cd + (long)s * 65536 + (long)j0 * L;

    const int tid  = threadIdx.x;
    const int w    = tid >> 6;
    const int lane = tid & 63;
    const int ag   = w & 3;      // a-group: a in [64*ag, 64*ag+64)
    const int bh   = w >> 2;     // b-half:  b in [128*bh, 128*bh+128)
    const int ta   = lane & 15;  // a-quad within group
    const int jq   = lane >> 4;  // j-quad (0..3)
    const int a_base = ag * 64 + ta * 4;
    const int j_base = jq * 4;

    // staging: per-lane global byte offset within the wave's slice
    // row-in-tile = 4c + (lane>>4), col bytes = ag*256 + (lane&15)*16
    const int glane = (bh * 128 + jq) * 1024 + ag * 256 + ta * 16;
    char* const ldst = (char*)Kw + w * 8192 + lane * 16;

    // per-thread update constants: cc[ji][ai] = c[j_base+ji][a_base+ai], same for r
    float cc[4][4], rr[4][4];
    if (bh == 0) {
#pragma unroll
        for (int ji = 0; ji < 4; ji++) {
            float4 cv = *(const float4*)&Cp[(j_base + ji) * L + a_base];
            float4 rv = *(const float4*)&Rp[(j_base + ji) * L + a_base];
            cc[ji][0] = cv.x; cc[ji][1] = cv.y; cc[ji][2] = cv.z; cc[ji][3] = cv.w;
            rr[ji][0] = rv.x; rr[ji][1] = rv.y; rr[ji][2] = rv.z; rr[ji][3] = rv.w;
        }
    }

    for (int idx = tid; idx < 5120; idx += 512) Uc[idx] = 1.0f / L;
    __syncthreads();

    float acc[4][4];

    auto stage = [&](const char* Mgb, int t, int buf) {
        const char* g = Mgb + glane + t * 16384;
        char* l = ldst + (buf << 12);
        GLL16(g,         l);
        GLL16(g + 4096,  l + 1024);
        GLL16(g + 8192,  l + 2048);
        GLL16(g + 12288, l + 3072);
    };

    auto run_pass = [&](const char* __restrict__ Mgb, const float* __restrict__ S) {
#pragma unroll
        for (int ai = 0; ai < 4; ai++)
#pragma unroll
            for (int ji = 0; ji < 4; ji++) acc[ai][ji] = 0.f;
        stage(Mgb, 0, 0);
        const float* Sj = S + 4 * jq;
        for (int t = 0; t < 8; t++) {
            WAITLGKM0();                 // prior-tile ds_reads fully drained
            if (t < 7) {
                stage(Mgb, t + 1, (t + 1) & 1);
                WAITVM4();               // tile t's four loads have landed
            } else {
                WAITVM0();
            }
            const float* Kt = Kw + w * 2048 + ((t & 1) << 10) + ta * 4;
            const float* St = Sj + (bh * 128 + t * 16) * 20;
#pragma unroll
            for (int bbi = 0; bbi < 16; bbi++) {
                float4 kv = *(const float4*)(Kt + bbi * 64);
                float4 sv = *(const float4*)(St + bbi * 20);
                float kk[4] = {kv.x, kv.y, kv.z, kv.w};
                float ss[4] = {sv.x, sv.y, sv.z, sv.w};
#pragma unroll
                for (int ai = 0; ai < 4; ai++)
#pragma unroll
                    for (int ji = 0; ji < 4; ji++)
                        acc[ai][ji] = fmaf(kk[ai], ss[ji], acc[ai][ji]);
            }
        }
    };

    const int slot = (ag * 64 + lane) * 20;

    auto reduce_update = [&](float* __restrict__ dst, const float (*cr)[4]) {
        if (bh == 1) {
#pragma unroll
            for (int ai = 0; ai < 4; ai++) {
                float4 o;
                o.x = acc[ai][0]; o.y = acc[ai][1]; o.z = acc[ai][2]; o.w = acc[ai][3];
                *(float4*)&Sc[slot + 4 * ai] = o;
            }
        }
        __syncthreads();
        if (bh == 0) {
#pragma unroll
            for (int ai = 0; ai < 4; ai++) {
                float4 p = *(const float4*)&Sc[slot + 4 * ai];
                float s0 = acc[ai][0] + p.x;
                float s1 = acc[ai][1] + p.y;
                float s2 = acc[ai][2] + p.z;
                float s3 = acc[ai][3] + p.w;
                float4 o;
                o.x = cr[0][ai] / (s0 + EPSF);
                o.y = cr[1][ai] / (s1 + EPSF);
                o.z = cr[2][ai] / (s2 + EPSF);
                o.w = cr[3][ai] / (s3 + EPSF);
                *(float4*)&dst[(a_base + ai) * 20 + j_base] = o;
            }
        }
        __syncthreads();
    };

    for (int it = 0; it < NITER; it++) {
        run_pass(Kpb, Uc);          // acc = K^T u (partial per b-half)
        reduce_update(Tc, cc);      // T = c/(K^T u + eps)
        run_pass(Kpb, Tc);
        reduce_update(Uc, rr);      // U = r/(K^T t + eps)
    }
    // final V pass: V = c/(K^T u + eps) -> Tc
    run_pass(Kpb, Uc);
    reduce_update(Tc, cc);
    // loss pass: acc = KM^T v ; lp = sum U * acc
    run_pass(KMpb, Tc);
    float lp = 0.f;
    if (bh == 1) {
#pragma unroll
        for (int ai = 0; ai < 4; ai++) {
            float4 o;
            o.x = acc[ai][0]; o.y = acc[ai][1]; o.z = acc[ai][2]; o.w = acc[ai][3];
            *(float4*)&Sc[slot + 4 * ai] = o;
        }
    }
    __syncthreads();
    if (bh == 0) {
#pragma unroll
        for (int ai = 0; ai < 4; ai++) {
            float4 p = *(const float4*)&Sc[slot + 4 * ai];
            float4 u = *(const float4*)&Uc[(a_base + ai) * 20 + j_base];
            lp += u.x * (acc[ai][0] + p.x);
            lp += u.y * (acc[ai][1] + p.y);
            lp += u.z * (acc[ai][2] + p.z);
            lp += u.w * (acc[ai][3] + p.w);
        }
    }
    // block reduction (reuse Tc — fully consumed)
    Tc[tid] = lp;
    __syncthreads();
    for (int o = 256; o >= 1; o >>= 1) {
        if (tid < o) Tc[tid] += Tc[tid + o];
        __syncthreads();
    }
    if (tid == 0) lossbuf[bid] = Tc[0];
}

// ---------------------------------------------------------------------------
// K7: final sum  (unchanged)
// ---------------------------------------------------------------------------
__global__ __launch_bounds__(256) void k_final(
    const float* __restrict__ lossbuf, float* __restrict__ out)
{
    __shared__ float red[256];
    int t = threadIdx.x;
    red[t] = lossbuf[t];
    __syncthreads();
    for (int o = 128; o >= 1; o >>= 1) {
        if (t < o) red[t] += red[t + o];
        __syncthreads();
    }
    if (t == 0) out[0] = red[0];
}

extern "C" void kernel_launch(void* const* d_in, const int* in_sizes, int n_in,
                              void* d_out, int out_size, void* d_ws, size_t ws_size,
                              hipStream_t stream)
{
    const float* f    = (const float*)d_in[0];
    const float* head = (const float*)d_in[1];
    const float* W1   = (const float*)d_in[2];
    const float* b1   = (const float*)d_in[3];
    const float* W2   = (const float*)d_in[4];
    const float* b2   = (const float*)d_in[5];
    float* scores = (float*)d_out;
    float* wloss  = scores + (long)NB * L * L;

    float* ws      = (float*)d_ws;
    float* C       = ws;
    float* Km      = ws + 1 * 1048576;
    float* KMm     = ws + 2 * 1048576;
    float* R       = ws + 3 * 1048576;
    float* Cd      = ws + 4 * 1048576;
    float* maxabs  = ws + 5 * 1048576;
    float* lossbuf = maxabs + 64;

    k_scores<<<16384, 256, 0, stream>>>(f, W1, b1, W2, b2, scores);
    k_cost  <<<4096,  256, 0, stream>>>(f, C);
    k_absmax<<<NB,    256, 0, stream>>>(C, maxabs);
    k_kmat  <<<2048,  512, 0, stream>>>(C, maxabs, Km, KMm);
    k_rc    <<<NB * L, 256, 0, stream>>>(scores, head, R, Cd);
    k_sink  <<<NB * 16, 512, 0, stream>>>(Km, KMm, R, Cd, lossbuf);
    k_final <<<1, 256, 0, stream>>>(lossbuf, wloss);
}

// Round 4
// 1566.897 us; speedup vs baseline: 1.1025x; 1.0186x over previous
//
#include <hip/hip_runtime.h>
#include <math.h>

#define NB 16
#define L 256
#define H 128
#define HID 128
#define LAMF 20.0f
#define EPSF 1e-8f
#define NITER 20

// async global->LDS, 16B per lane
#define GLL16(gp, lp) __builtin_amdgcn_global_load_lds( \
    (const __attribute__((address_space(1))) unsigned int*)(gp), \
    (__attribute__((address_space(3))) unsigned int*)(lp), 16, 0, 0)
// s_waitcnt encodings (gfx9): vmcnt low [3:0], exp [6:4], lgkm [11:8], vmcnt hi [15:14]
#define WAITVM4() __builtin_amdgcn_s_waitcnt(0x0F74)  // vmcnt(4), lgkm/exp nowait
#define WAITVM0() __builtin_amdgcn_s_waitcnt(0x0F70)  // vmcnt(0)
#define WAITLGKM0() __builtin_amdgcn_s_waitcnt(0xC07F) // lgkmcnt(0), vm/exp nowait

// ---------------------------------------------------------------------------
// K1 v2: scores = tanh(f @ W1 + b1) @ W2 + b2
// 128x128 block tile (grid 8192), 8x8 per-thread register tile.
// 64 FMA per 4 ds_read_b128 per k-step (2x arithmetic intensity vs v1);
// As reads are 4-address broadcast (conflict-free), Bs reads 16-address.
// k-accumulation order per (row,col) unchanged -> scores ~bit-identical.
// ---------------------------------------------------------------------------
__global__ __launch_bounds__(256) void k_scores(
    const float* __restrict__ f, const float* __restrict__ W1,
    const float* __restrict__ b1, const float* __restrict__ W2,
    const float* __restrict__ b2, float* __restrict__ scores)
{
    __shared__ float As[32][132];   // [k][m]
    __shared__ float Bs[32][132];   // [k][n]
    const int tid = threadIdx.x;
    const int tx = tid & 15;        // col group: cols [8*tx, 8*tx+8)
    const int ty = tid >> 4;        // row group: rows [8*ty, 8*ty+8)
    const long m0 = (long)blockIdx.x * 128;

    float acc[8][8];
#pragma unroll
    for (int i = 0; i < 8; i++)
#pragma unroll
        for (int c = 0; c < 8; c++) acc[i][c] = 0.f;

    for (int kc = 0; kc < H; kc += 32) {
        // stage As: 128 m x 32 k  (coalesced 128B global reads per half-wave)
        {
            const int k = tid & 31, mb = tid >> 5;
#pragma unroll
            for (int r = 0; r < 16; r++) {
                int m = r * 8 + mb;
                As[k][m] = f[(m0 + m) * H + kc + k];
            }
        }
        // stage Bs: 32 k x 128 n
        {
#pragma unroll
            for (int r = 0; r < 16; r++) {
                int idx = r * 256 + tid;
                int k = idx >> 7, n = idx & 127;
                Bs[k][n] = W1[(kc + k) * HID + n];
            }
        }
        __syncthreads();
#pragma unroll
        for (int k = 0; k < 32; k++) {
            float4 a0 = *(const float4*)&As[k][ty * 8];
            float4 a1 = *(const float4*)&As[k][ty * 8 + 4];
            float4 q0 = *(const float4*)&Bs[k][tx * 8];
            float4 q1 = *(const float4*)&Bs[k][tx * 8 + 4];
            float av[8] = {a0.x, a0.y, a0.z, a0.w, a1.x, a1.y, a1.z, a1.w};
            float bv[8] = {q0.x, q0.y, q0.z, q0.w, q1.x, q1.y, q1.z, q1.w};
#pragma unroll
            for (int i = 0; i < 8; i++)
#pragma unroll
                for (int c = 0; c < 8; c++)
                    acc[i][c] = fmaf(av[i], bv[c], acc[i][c]);
        }
        __syncthreads();
    }
    // epilogue: tanh + W2 dot; reduce across tx (low 4 lane bits)
    float part[8];
#pragma unroll
    for (int i = 0; i < 8; i++) part[i] = 0.f;
#pragma unroll
    for (int c = 0; c < 8; c++) {
        int col = tx * 8 + c;
        float b1v = b1[col], w2v = W2[col];
#pragma unroll
        for (int i = 0; i < 8; i++) {
            float hv = tanhf(acc[i][c] + b1v);
            part[i] = fmaf(hv, w2v, part[i]);
        }
    }
#pragma unroll
    for (int off = 8; off >= 1; off >>= 1)
#pragma unroll
        for (int i = 0; i < 8; i++)
            part[i] += __shfl_xor(part[i], off, 64);
    if (tx == 0) {
        float b2v = b2[0];
#pragma unroll
        for (int i = 0; i < 8; i++)
            scores[m0 + ty * 8 + i] = part[i] + b2v;
    }
}

// ---------------------------------------------------------------------------
// K2: C[s,i,j] = dot128(f[s,i,j,:], f[s,j,i,:])  (unchanged)
// ---------------------------------------------------------------------------
__global__ __launch_bounds__(256) void k_cost(
    const float* __restrict__ f, float* __restrict__ C)
{
    const int bid = blockIdx.x;
    const int s = bid >> 8, i = bid & 255;
    const int wave = threadIdx.x >> 6, lane = threadIdx.x & 63;
    const long base_i = ((long)(s * L + i)) * L;
    for (int j4 = i; j4 < L; j4 += 4) {
        int j = j4 + wave;
        if (j < L) {
            const float2 x = *(const float2*)&f[(base_i + j) * (long)H + lane * 2];
            const float2 y = *(const float2*)&f[(((long)(s * L + j)) * L + i) * (long)H + lane * 2];
            float d = fmaf(x.x, y.x, x.y * y.y);
#pragma unroll
            for (int off = 32; off >= 1; off >>= 1) d += __shfl_xor(d, off, 64);
            if (lane == 0) {
                C[base_i + j] = d;
                C[((long)(s * L + j)) * L + i] = d;
            }
        }
    }
}

// ---------------------------------------------------------------------------
// K3: per-sample max |C|  (unchanged)
// ---------------------------------------------------------------------------
__global__ __launch_bounds__(256) void k_absmax(
    const float* __restrict__ C, float* __restrict__ maxabs)
{
    __shared__ float red[256];
    const int s = blockIdx.x, tid = threadIdx.x;
    const float* Cp = C + (long)s * L * L;
    float m = 0.f;
    for (int idx = tid; idx < L * L; idx += 256) m = fmaxf(m, fabsf(Cp[idx]));
    red[tid] = m;
    __syncthreads();
    for (int o = 128; o >= 1; o >>= 1) {
        if (tid < o) red[tid] = fmaxf(red[tid], red[tid + o]);
        __syncthreads();
    }
    if (tid == 0) maxabs[s] = red[0];
}

// ---------------------------------------------------------------------------
// K4: Kmat = exp(-LAM*Cn), KM = Kmat*Cn  (unchanged)
// ---------------------------------------------------------------------------
__global__ __launch_bounds__(512) void k_kmat(
    const float* __restrict__ C, const float* __restrict__ maxabs,
    float* __restrict__ Km, float* __restrict__ KMm)
{
    long idx = (long)blockIdx.x * blockDim.x + threadIdx.x;
    const long tot = (long)NB * L * L;
    for (; idx < tot; idx += (long)gridDim.x * blockDim.x) {
        int s = (int)(idx >> 16);
        float cn = C[idx] / (maxabs[s] + EPSF);
        float kv = __expf(-LAMF * cn);
        Km[idx] = kv;
        KMm[idx] = kv * cn;
    }
}

// ---------------------------------------------------------------------------
// K5: r = softmax(scores row), c = (head+EPS)/rowsum  (unchanged)
// ---------------------------------------------------------------------------
__global__ __launch_bounds__(256) void k_rc(
    const float* __restrict__ scores, const float* __restrict__ head,
    float* __restrict__ R, float* __restrict__ Cd)
{
    __shared__ float red[256];
    const long base = (long)blockIdx.x * L;
    const int t = threadIdx.x;
    float sc = scores[base + t];
    red[t] = sc;
    __syncthreads();
    for (int o = 128; o >= 1; o >>= 1) {
        if (t < o) red[t] = fmaxf(red[t], red[t + o]);
        __syncthreads();
    }
    float mx = red[0];
    __syncthreads();
    float e = __expf(sc - mx);
    red[t] = e;
    __syncthreads();
    for (int o = 128; o >= 1; o >>= 1) {
        if (t < o) red[t] += red[t + o];
        __syncthreads();
    }
    float es = red[0];
    __syncthreads();
    R[base + t] = e / es;
    float hv = head[base + t] + EPSF;
    red[t] = hv;
    __syncthreads();
    for (int o = 128; o >= 1; o >>= 1) {
        if (t < o) red[t] += red[t + o];
        __syncthreads();
    }
    float hs = red[0];
    Cd[base + t] = hv / hs;
}

// ---------------------------------------------------------------------------
// K6: Sinkhorn v3 — 4a x 4j thread tile (16 FMA per 2 ds_read_b128), b-dim
// split across wave halves, per-pass cross-half reduction via LDS scratch.
// (unchanged from round 3)
// ---------------------------------------------------------------------------
__global__ __launch_bounds__(512) void k_sink(
    const float* __restrict__ Km, const float* __restrict__ KMm,
    const float* __restrict__ R, const float* __restrict__ Cd,
    float* __restrict__ lossbuf)
{
    __shared__ __align__(128) float Kw[16384];  // [wave][buf][16 rows x 64 cols]
    __shared__ __align__(128) float Uc[5120];   // [256 b][20] (16 j + pad)
    __shared__ __align__(128) float Tc[5120];
    __shared__ __align__(128) float Sc[5120];   // reduction scratch

    const int bid = blockIdx.x;
    const int s = bid >> 4;
    const int j0 = (bid & 15) * 16;
    const char* Kpb  = (const char*)(Km  + (long)s * 65536);
    const char* KMpb = (const char*)(KMm + (long)s * 65536);
    const float* Rp  = R  + (long)s * 65536 + (long)j0 * L;
    const float* Cp  = Cd + (long)s * 65536 + (long)j0 * L;

    const int tid  = threadIdx.x;
    const int w    = tid >> 6;
    const int lane = tid & 63;
    const int ag   = w & 3;      // a-group: a in [64*ag, 64*ag+64)
    const int bh   = w >> 2;     // b-half:  b in [128*bh, 128*bh+128)
    const int ta   = lane & 15;  // a-quad within group
    const int jq   = lane >> 4;  // j-quad (0..3)
    const int a_base = ag * 64 + ta * 4;
    const int j_base = jq * 4;

    const int glane = (bh * 128 + jq) * 1024 + ag * 256 + ta * 16;
    char* const ldst = (char*)Kw + w * 8192 + lane * 16;

    float cc[4][4], rr[4][4];
    if (bh == 0) {
#pragma unroll
        for (int ji = 0; ji < 4; ji++) {
            float4 cv = *(const float4*)&Cp[(j_base + ji) * L + a_base];
            float4 rv = *(const float4*)&Rp[(j_base + ji) * L + a_base];
            cc[ji][0] = cv.x; cc[ji][1] = cv.y; cc[ji][2] = cv.z; cc[ji][3] = cv.w;
            rr[ji][0] = rv.x; rr[ji][1] = rv.y; rr[ji][2] = rv.z; rr[ji][3] = rv.w;
        }
    }

    for (int idx = tid; idx < 5120; idx += 512) Uc[idx] = 1.0f / L;
    __syncthreads();

    float acc[4][4];

    auto stage = [&](const char* Mgb, int t, int buf) {
        const char* g = Mgb + glane + t * 16384;
        char* l = ldst + (buf << 12);
        GLL16(g,         l);
        GLL16(g + 4096,  l + 1024);
        GLL16(g + 8192,  l + 2048);
        GLL16(g + 12288, l + 3072);
    };

    auto run_pass = [&](const char* __restrict__ Mgb, const float* __restrict__ S) {
#pragma unroll
        for (int ai = 0; ai < 4; ai++)
#pragma unroll
            for (int ji = 0; ji < 4; ji++) acc[ai][ji] = 0.f;
        stage(Mgb, 0, 0);
        const float* Sj = S + 4 * jq;
        for (int t = 0; t < 8; t++) {
            WAITLGKM0();                 // prior-tile ds_reads fully drained
            if (t < 7) {
                stage(Mgb, t + 1, (t + 1) & 1);
                WAITVM4();               // tile t's four loads have landed
            } else {
                WAITVM0();
            }
            const float* Kt = Kw + w * 2048 + ((t & 1) << 10) + ta * 4;
            const float* St = Sj + (bh * 128 + t * 16) * 20;
#pragma unroll
            for (int bbi = 0; bbi < 16; bbi++) {
                float4 kv = *(const float4*)(Kt + bbi * 64);
                float4 sv = *(const float4*)(St + bbi * 20);
                float kk[4] = {kv.x, kv.y, kv.z, kv.w};
                float ss[4] = {sv.x, sv.y, sv.z, sv.w};
#pragma unroll
                for (int ai = 0; ai < 4; ai++)
#pragma unroll
                    for (int ji = 0; ji < 4; ji++)
                        acc[ai][ji] = fmaf(kk[ai], ss[ji], acc[ai][ji]);
            }
        }
    };

    const int slot = (ag * 64 + lane) * 20;

    auto reduce_update = [&](float* __restrict__ dst, const float (*cr)[4]) {
        if (bh == 1) {
#pragma unroll
            for (int ai = 0; ai < 4; ai++) {
                float4 o;
                o.x = acc[ai][0]; o.y = acc[ai][1]; o.z = acc[ai][2]; o.w = acc[ai][3];
                *(float4*)&Sc[slot + 4 * ai] = o;
            }
        }
        __syncthreads();
        if (bh == 0) {
#pragma unroll
            for (int ai = 0; ai < 4; ai++) {
                float4 p = *(const float4*)&Sc[slot + 4 * ai];
                float s0 = acc[ai][0] + p.x;
                float s1 = acc[ai][1] + p.y;
                float s2 = acc[ai][2] + p.z;
                float s3 = acc[ai][3] + p.w;
                float4 o;
                o.x = cr[0][ai] / (s0 + EPSF);
                o.y = cr[1][ai] / (s1 + EPSF);
                o.z = cr[2][ai] / (s2 + EPSF);
                o.w = cr[3][ai] / (s3 + EPSF);
                *(float4*)&dst[(a_base + ai) * 20 + j_base] = o;
            }
        }
        __syncthreads();
    };

    for (int it = 0; it < NITER; it++) {
        run_pass(Kpb, Uc);          // acc = K^T u (partial per b-half)
        reduce_update(Tc, cc);      // T = c/(K^T u + eps)
        run_pass(Kpb, Tc);
        reduce_update(Uc, rr);      // U = r/(K^T t + eps)
    }
    // final V pass: V = c/(K^T u + eps) -> Tc
    run_pass(Kpb, Uc);
    reduce_update(Tc, cc);
    // loss pass: acc = KM^T v ; lp = sum U * acc
    run_pass(KMpb, Tc);
    float lp = 0.f;
    if (bh == 1) {
#pragma unroll
        for (int ai = 0; ai < 4; ai++) {
            float4 o;
            o.x = acc[ai][0]; o.y = acc[ai][1]; o.z = acc[ai][2]; o.w = acc[ai][3];
            *(float4*)&Sc[slot + 4 * ai] = o;
        }
    }
    __syncthreads();
    if (bh == 0) {
#pragma unroll
        for (int ai = 0; ai < 4; ai++) {
            float4 p = *(const float4*)&Sc[slot + 4 * ai];
            float4 u = *(const float4*)&Uc[(a_base + ai) * 20 + j_base];
            lp += u.x * (acc[ai][0] + p.x);
            lp += u.y * (acc[ai][1] + p.y);
            lp += u.z * (acc[ai][2] + p.z);
            lp += u.w * (acc[ai][3] + p.w);
        }
    }
    // block reduction (reuse Tc — fully consumed)
    Tc[tid] = lp;
    __syncthreads();
    for (int o = 256; o >= 1; o >>= 1) {
        if (tid < o) Tc[tid] += Tc[tid + o];
        __syncthreads();
    }
    if (tid == 0) lossbuf[bid] = Tc[0];
}

// ---------------------------------------------------------------------------
// K7: final sum  (unchanged)
// ---------------------------------------------------------------------------
__global__ __launch_bounds__(256) void k_final(
    const float* __restrict__ lossbuf, float* __restrict__ out)
{
    __shared__ float red[256];
    int t = threadIdx.x;
    red[t] = lossbuf[t];
    __syncthreads();
    for (int o = 128; o >= 1; o >>= 1) {
        if (t < o) red[t] += red[t + o];
        __syncthreads();
    }
    if (t == 0) out[0] = red[0];
}

extern "C" void kernel_launch(void* const* d_in, const int* in_sizes, int n_in,
                              void* d_out, int out_size, void* d_ws, size_t ws_size,
                              hipStream_t stream)
{
    const float* f    = (const float*)d_in[0];
    const float* head = (const float*)d_in[1];
    const float* W1   = (const float*)d_in[2];
    const float* b1   = (const float*)d_in[3];
    const float* W2   = (const float*)d_in[4];
    const float* b2   = (const float*)d_in[5];
    float* scores = (float*)d_out;
    float* wloss  = scores + (long)NB * L * L;

    float* ws      = (float*)d_ws;
    float* C       = ws;
    float* Km      = ws + 1 * 1048576;
    float* KMm     = ws + 2 * 1048576;
    float* R       = ws + 3 * 1048576;
    float* Cd      = ws + 4 * 1048576;
    float* maxabs  = ws + 5 * 1048576;
    float* lossbuf = maxabs + 64;

    k_scores<<<8192,  256, 0, stream>>>(f, W1, b1, W2, b2, scores);
    k_cost  <<<4096,  256, 0, stream>>>(f, C);
    k_absmax<<<NB,    256, 0, stream>>>(C, maxabs);
    k_kmat  <<<2048,  512, 0, stream>>>(C, maxabs, Km, KMm);
    k_rc    <<<NB * L, 256, 0, stream>>>(scores, head, R, Cd);
    k_sink  <<<NB * 16, 512, 0, stream>>>(Km, KMm, R, Cd, lossbuf);
    k_final <<<1, 256, 0, stream>>>(lossbuf, wloss);
}